// Round 1
// baseline (8950.982 us; speedup 1.0000x reference)
//
#include <hip/hip_runtime.h>
#include <hip/hip_bf16.h>
#include <math.h>

// Problem constants (from reference)
#define RESV 128
#define V3 (RESV*RESV*RESV)          // 2097152 voxels per channel
#define N_RAYS 1024
#define N_SAMPLES 891                // int(257*sqrt(3)/0.5)+1
#define STEP_T 0.0078125f            // STEPSIZE * VOXEL = 0.5 * (2/128)
#define ACT_SHIFT -4.595119850134589f // log(1/(1-0.01) - 1)

// ---------------------------------------------------------------------------
// Kernel A: 3-channel 5x5x5 cross-correlation (zero pad 2) over density
// channel, then per-voxel negate+normalize. Output packed float3 per voxel.
// ---------------------------------------------------------------------------
__global__ __launch_bounds__(256)
void normals_conv_kernel(const float* __restrict__ grid,
                         const float* __restrict__ sobel,
                         float* __restrict__ nout) {
    __shared__ float sk[375];
    const int t = threadIdx.x;
    for (int i = t; i < 375; i += 256) sk[i] = sobel[i];
    __syncthreads();

    const int gid = blockIdx.x * 256 + t;      // 0 .. V3-1
    const int iz = gid & 127;
    const int iy = (gid >> 7) & 127;
    const int ix = gid >> 14;

    float c0 = 0.f, c1 = 0.f, c2 = 0.f;
    #pragma unroll
    for (int da = -2; da <= 2; ++da) {
        int a = ix + da;
        if ((unsigned)a >= 128u) continue;
        #pragma unroll
        for (int db = -2; db <= 2; ++db) {
            int b = iy + db;
            if ((unsigned)b >= 128u) continue;
            const float* row = grid + (a * 128 + b) * 128;
            const float* k0  = sk + ((da + 2) * 5 + (db + 2)) * 5;
            #pragma unroll
            for (int dc = -2; dc <= 2; ++dc) {
                int c = iz + dc;
                if ((unsigned)c >= 128u) continue;
                float g = row[c];
                c0 = fmaf(g, k0[dc + 2],       c0);
                c1 = fmaf(g, k0[125 + dc + 2], c1);
                c2 = fmaf(g, k0[250 + dc + 2], c2);
            }
        }
    }
    float l   = sqrtf(c0 * c0 + c1 * c1 + c2 * c2);
    float inv = -1.0f / fmaxf(l, 1e-12f);   // nrm = -nrm / max(||nrm||,1e-12)
    float* o = nout + (size_t)gid * 3;
    o[0] = c0 * inv; o[1] = c1 * inv; o[2] = c2 * inv;
}

// ---------------------------------------------------------------------------
// MLP layer helper: 16 float4 output groups, weights from LDS (wave-uniform
// broadcast ds_read_b128). Fully unrolled so in/out arrays stay in VGPRs.
// ---------------------------------------------------------------------------
template <int NIN>
__device__ __forceinline__ void layer_relu(const float* in, float* outv,
                                           const float* W, const float* B) {
    #pragma unroll
    for (int o4 = 0; o4 < 16; ++o4) {
        const float4 bv = *(const float4*)&B[o4 * 4];
        float ax = bv.x, ay = bv.y, az = bv.z, aw = bv.w;
        #pragma unroll
        for (int i = 0; i < NIN; ++i) {
            const float4 wv = *(const float4*)&W[i * 64 + o4 * 4];
            const float fv = in[i];
            ax = fmaf(fv, wv.x, ax); ay = fmaf(fv, wv.y, ay);
            az = fmaf(fv, wv.z, az); aw = fmaf(fv, wv.w, aw);
        }
        outv[o4 * 4 + 0] = fmaxf(ax, 0.f);
        outv[o4 * 4 + 1] = fmaxf(ay, 0.f);
        outv[o4 * 4 + 2] = fmaxf(az, 0.f);
        outv[o4 * 4 + 3] = fmaxf(aw, 0.f);
    }
}

// ---------------------------------------------------------------------------
// Kernel B: one block per ray. 256 threads, thread t owns samples
// s = j*256 + t (wave = 64 consecutive samples -> coherent gathers).
// ---------------------------------------------------------------------------
__global__ __launch_bounds__(256)
void raymarch_kernel(const float* __restrict__ ro, const float* __restrict__ rd,
                     const float* __restrict__ vd, const float* __restrict__ grid,
                     const float* __restrict__ nrm,
                     const float* __restrict__ w0, const float* __restrict__ b0,
                     const float* __restrict__ w1, const float* __restrict__ b1,
                     const float* __restrict__ w2, const float* __restrict__ b2,
                     const float* __restrict__ w3, const float* __restrict__ b3,
                     float* __restrict__ out) {
    __shared__ __align__(16) float sw0[54 * 64];
    __shared__ __align__(16) float sw1[64 * 64];
    __shared__ __align__(16) float sw2[64 * 64];
    __shared__ __align__(16) float sw3[64 * 3];
    __shared__ __align__(16) float sb0[64], sb1[64], sb2[64];
    __shared__ float sb3[4];
    __shared__ float lgl[1024];
    __shared__ float aux[256];
    __shared__ float red[12];

    const int t = threadIdx.x;
    const int ray = blockIdx.x;

    for (int i = t; i < 54 * 64; i += 256) sw0[i] = w0[i];
    for (int i = t; i < 64 * 64; i += 256) sw1[i] = w1[i];
    for (int i = t; i < 64 * 64; i += 256) sw2[i] = w2[i];
    for (int i = t; i < 64 * 3;  i += 256) sw3[i] = w3[i];
    if (t < 64) { sb0[t] = b0[t]; sb1[t] = b1[t]; sb2[t] = b2[t]; }
    if (t < 3) sb3[t] = b3[t];
    if (t == 3) sb3[3] = 0.f;
    __syncthreads();

    const float ox = ro[ray * 3 + 0], oy = ro[ray * 3 + 1], oz = ro[ray * 3 + 2];
    const float dx = rd[ray * 3 + 0], dyv = rd[ray * 3 + 1], dzv = rd[ray * 3 + 2];
    const float vx = vd[ray * 3 + 0], vy = vd[ray * 3 + 1], vz = vd[ray * 3 + 2];

    // ray-box entry/exit (reference semantics)
    const float ex = (dx  == 0.f) ? 1e-6f : dx;
    const float ey = (dyv == 0.f) ? 1e-6f : dyv;
    const float ez = (dzv == 0.f) ? 1e-6f : dzv;
    const float rax = (1.f - ox) / ex, rbx = (-1.f - ox) / ex;
    const float ray_ = (1.f - oy) / ey, rby = (-1.f - oy) / ey;
    const float raz = (1.f - oz) / ez, rbz = (-1.f - oz) / ez;
    float tmin = fmaxf(fmaxf(fminf(rax, rbx), fminf(ray_, rby)), fminf(raz, rbz));
    float tmax = fminf(fminf(fmaxf(rax, rbx), fmaxf(ray_, rby)), fmaxf(raz, rbz));
    tmin = fminf(fmaxf(tmin, 0.2f), 3.0f);
    tmax = fminf(fmaxf(tmax, 0.2f), 3.0f);
    const bool mask_ray = (tmax <= tmin);
    const float invn = 1.0f / sqrtf(dx * dx + dyv * dyv + dzv * dzv);

    float alphas[4];
    float colr[4], colg[4], colb[4];

    for (int j = 0; j < 4; ++j) {
        alphas[j] = 0.f; colr[j] = 0.f; colg[j] = 0.f; colb[j] = 0.f;
        const int s = j * 256 + t;
        if (s >= N_SAMPLES || mask_ray) continue;
        const float ti = tmin + STEP_T * (float)s * invn;
        const float px = fmaf(dx, ti, ox);
        const float py = fmaf(dyv, ti, oy);
        const float pz = fmaf(dzv, ti, oz);
        if (px < -1.f || px > 1.f || py < -1.f || py > 1.f || pz < -1.f || pz > 1.f)
            continue;

        // trilinear setup; grid flat index = (ia*128 + ib)*128 + ic,
        // ia from px (outermost), ib from py, ic from pz (innermost).
        const float ga = (px + 1.f) * 63.5f;
        const float gb = (py + 1.f) * 63.5f;
        const float gc = (pz + 1.f) * 63.5f;
        const float fla = floorf(ga), flb = floorf(gb), flc = floorf(gc);
        const float fa = ga - fla, fb = gb - flb, fc = gc - flc;
        int ia0 = min(max((int)fla, 0), 127);
        int ib0 = min(max((int)flb, 0), 127);
        int ic0 = min(max((int)flc, 0), 127);
        int ia1 = min(ia0 + 1, 127);
        int ib1 = min(ib0 + 1, 127);
        int ic1 = min(ic0 + 1, 127);
        const int base00 = (ia0 * 128 + ib0) * 128;
        const int base01 = (ia0 * 128 + ib1) * 128;
        const int base10 = (ia1 * 128 + ib0) * 128;
        const int base11 = (ia1 * 128 + ib1) * 128;
        int idxs[8] = { base00 + ic0, base00 + ic1, base01 + ic0, base01 + ic1,
                        base10 + ic0, base10 + ic1, base11 + ic0, base11 + ic1 };
        const float wa0 = 1.f - fa, wb0 = 1.f - fb, wc0 = 1.f - fc;
        float w8[8] = { wa0 * wb0 * wc0, wa0 * wb0 * fc, wa0 * fb * wc0, wa0 * fb * fc,
                        fa  * wb0 * wc0, fa  * wb0 * fc, fa  * fb * wc0, fa  * fb * fc };

        float lat[16];
        #pragma unroll
        for (int c = 0; c < 16; ++c) {
            const float* gcp = grid + (size_t)c * V3;
            float acc = 0.f;
            #pragma unroll
            for (int k = 0; k < 8; ++k) acc = fmaf(w8[k], gcp[idxs[k]], acc);
            lat[c] = acc;
        }
        float n0 = 0.f, n1 = 0.f, n2 = 0.f;
        #pragma unroll
        for (int k = 0; k < 8; ++k) {
            const float* npk = nrm + (size_t)idxs[k] * 3;
            n0 = fmaf(w8[k], npk[0], n0);
            n1 = fmaf(w8[k], npk[1], n1);
            n2 = fmaf(w8[k], npk[2], n2);
        }
        const float nl = sqrtf(n0 * n0 + n1 * n1 + n2 * n2);
        const float ninv = -1.0f / fmaxf(nl, 1e-12f);
        n0 *= ninv; n1 *= ninv; n2 *= ninv;
        const float dotv = -(vx * n0 + vy * n1 + vz * n2);
        const float rx = fmaf(2.f * dotv, n0, vx);
        const float ry = fmaf(2.f * dotv, n1, vy);
        const float rz = fmaf(2.f * dotv, n2, vz);

        // alpha = 1 - exp(-softplus(lat0 + shift) * 0.5)
        const float d0 = lat[0] + ACT_SHIFT;
        const float sp = (d0 > 20.f) ? d0 : log1pf(expf(d0));
        alphas[j] = 1.f - expf(-sp * 0.5f);

        // feat = [rgb_lat(15), refdir(3), sin(18 freq-major), cos(18)]
        float feat[54];
        #pragma unroll
        for (int c = 0; c < 15; ++c) feat[c] = lat[c + 1];
        feat[15] = rx; feat[16] = ry; feat[17] = rz;
        float fr = 1.f;
        #pragma unroll
        for (int k = 0; k < 6; ++k) {
            feat[18 + k * 3 + 0] = sinf(rx * fr);
            feat[18 + k * 3 + 1] = sinf(ry * fr);
            feat[18 + k * 3 + 2] = sinf(rz * fr);
            feat[36 + k * 3 + 0] = cosf(rx * fr);
            feat[36 + k * 3 + 1] = cosf(ry * fr);
            feat[36 + k * 3 + 2] = cosf(rz * fr);
            fr *= 2.f;
        }

        float ha[64], hb[64];
        layer_relu<54>(feat, ha, sw0, sb0);
        layer_relu<64>(ha, hb, sw1, sb1);
        layer_relu<64>(hb, ha, sw2, sb2);
        float a0 = sb3[0], a1 = sb3[1], a2 = sb3[2];
        #pragma unroll
        for (int i = 0; i < 64; ++i) {
            a0 = fmaf(ha[i], sw3[i * 3 + 0], a0);
            a1 = fmaf(ha[i], sw3[i * 3 + 1], a1);
            a2 = fmaf(ha[i], sw3[i * 3 + 2], a2);
        }
        colr[j] = 1.f / (1.f + expf(-a0));
        colg[j] = 1.f / (1.f + expf(-a1));
        colb[j] = 1.f / (1.f + expf(-a2));
    }

    // log-space transmittance scan: lgl[s] = log(max(1-alpha,1e-10))
    #pragma unroll
    for (int j = 0; j < 4; ++j) {
        const int s = j * 256 + t;
        lgl[s] = logf(fmaxf(1.f - alphas[j], 1e-10f));
    }
    __syncthreads();
    // per-thread contiguous chunk inclusive scan
    float c0 = lgl[4 * t + 0];
    float c1 = c0 + lgl[4 * t + 1];
    float c2 = c1 + lgl[4 * t + 2];
    float c3 = c2 + lgl[4 * t + 3];
    lgl[4 * t + 0] = c0; lgl[4 * t + 1] = c1;
    lgl[4 * t + 2] = c2; lgl[4 * t + 3] = c3;
    aux[t] = c3;
    __syncthreads();
    // Hillis-Steele inclusive scan of chunk totals
    for (int off = 1; off < 256; off <<= 1) {
        const float v = (t >= off) ? aux[t - off] : 0.f;
        __syncthreads();
        aux[t] += v;
        __syncthreads();
    }
    const float total = aux[255];

    float r0 = 0.f, r1 = 0.f, r2 = 0.f;
    #pragma unroll
    for (int j = 0; j < 4; ++j) {
        const int s = j * 256 + t;
        if (s < N_SAMPLES && alphas[j] > 0.f) {
            float G;
            if (s == 0) G = 0.f;
            else {
                const int m = s - 1;
                G = lgl[m] + (((m >> 2) > 0) ? aux[(m >> 2) - 1] : 0.f);
            }
            const float T = expf(G);      // exclusive cumprod of (1-alpha)
            const float w = alphas[j] * T;
            r0 = fmaf(w, colr[j], r0);
            r1 = fmaf(w, colg[j], r1);
            r2 = fmaf(w, colb[j], r2);
        }
    }
    // block reduce (wave shuffle then LDS across 4 waves)
    #pragma unroll
    for (int off = 32; off > 0; off >>= 1) {
        r0 += __shfl_down(r0, off, 64);
        r1 += __shfl_down(r1, off, 64);
        r2 += __shfl_down(r2, off, 64);
    }
    if ((t & 63) == 0) {
        const int w = t >> 6;
        red[w * 3 + 0] = r0; red[w * 3 + 1] = r1; red[w * 3 + 2] = r2;
    }
    __syncthreads();
    if (t == 0) {
        const float Tf = expf(total);   // alphainv_cum[:, -1] * BG (BG=1)
        out[ray * 3 + 0] = red[0] + red[3] + red[6] + red[9]  + Tf;
        out[ray * 3 + 1] = red[1] + red[4] + red[7] + red[10] + Tf;
        out[ray * 3 + 2] = red[2] + red[5] + red[8] + red[11] + Tf;
    }
}

extern "C" void kernel_launch(void* const* d_in, const int* in_sizes, int n_in,
                              void* d_out, int out_size, void* d_ws, size_t ws_size,
                              hipStream_t stream) {
    (void)in_sizes; (void)n_in; (void)out_size; (void)ws_size;
    const float* ro    = (const float*)d_in[0];
    const float* rd    = (const float*)d_in[1];
    const float* vd    = (const float*)d_in[2];
    const float* grid  = (const float*)d_in[3];
    const float* sobel = (const float*)d_in[4];
    const float* w0 = (const float*)d_in[5];
    const float* b0 = (const float*)d_in[6];
    const float* w1 = (const float*)d_in[7];
    const float* b1 = (const float*)d_in[8];
    const float* w2 = (const float*)d_in[9];
    const float* b2 = (const float*)d_in[10];
    const float* w3 = (const float*)d_in[11];
    const float* b3 = (const float*)d_in[12];
    float* nrm = (float*)d_ws;                 // 3 * 128^3 floats = 25.2 MB

    normals_conv_kernel<<<V3 / 256, 256, 0, stream>>>(grid, sobel, nrm);
    raymarch_kernel<<<N_RAYS, 256, 0, stream>>>(ro, rd, vd, grid, nrm,
                                                w0, b0, w1, b1, w2, b2, w3, b3,
                                                (float*)d_out);
}

// Round 2
// 657.939 us; speedup vs baseline: 13.6046x; 13.6046x over previous
//
#include <hip/hip_runtime.h>
#include <hip/hip_bf16.h>
#include <math.h>

// Problem constants (from reference)
#define RESV 128
#define V3 (RESV*RESV*RESV)          // 2097152 voxels per channel
#define N_RAYS 1024
#define N_SAMPLES 891                // int(257*sqrt(3)/0.5)+1
#define STEP_T 0.0078125f            // STEPSIZE * VOXEL = 0.5 * (2/128)
#define ACT_SHIFT -4.595119850134589f // log(1/(1-0.01) - 1)

// ---------------------------------------------------------------------------
// Kernel A: 3-channel 5x5x5 cross-correlation (zero pad 2) over density
// channel, then per-voxel negate+normalize. Output packed float3 per voxel.
// ---------------------------------------------------------------------------
__global__ __launch_bounds__(256)
void normals_conv_kernel(const float* __restrict__ grid,
                         const float* __restrict__ sobel,
                         float* __restrict__ nout) {
    __shared__ float sk[375];
    const int t = threadIdx.x;
    for (int i = t; i < 375; i += 256) sk[i] = sobel[i];
    __syncthreads();

    const int gid = blockIdx.x * 256 + t;      // 0 .. V3-1
    const int iz = gid & 127;
    const int iy = (gid >> 7) & 127;
    const int ix = gid >> 14;

    float c0 = 0.f, c1 = 0.f, c2 = 0.f;
    #pragma unroll
    for (int da = -2; da <= 2; ++da) {
        int a = ix + da;
        if ((unsigned)a >= 128u) continue;
        #pragma unroll
        for (int db = -2; db <= 2; ++db) {
            int b = iy + db;
            if ((unsigned)b >= 128u) continue;
            const float* row = grid + (a * 128 + b) * 128;
            const float* k0  = sk + ((da + 2) * 5 + (db + 2)) * 5;
            #pragma unroll
            for (int dc = -2; dc <= 2; ++dc) {
                int c = iz + dc;
                if ((unsigned)c >= 128u) continue;
                float g = row[c];
                c0 = fmaf(g, k0[dc + 2],       c0);
                c1 = fmaf(g, k0[125 + dc + 2], c1);
                c2 = fmaf(g, k0[250 + dc + 2], c2);
            }
        }
    }
    float l   = sqrtf(c0 * c0 + c1 * c1 + c2 * c2);
    float inv = -1.0f / fmaxf(l, 1e-12f);   // nrm = -nrm / max(||nrm||,1e-12)
    float* o = nout + (size_t)gid * 3;
    o[0] = c0 * inv; o[1] = c1 * inv; o[2] = c2 * inv;
}

// ---------------------------------------------------------------------------
// MLP layer: inputs from a register array (length K), weights broadcast from
// LDS as float4, outputs (relu) written directly to the thread's private LDS
// row 4-at-a-time. Peak live registers ~= K + 8.
// ---------------------------------------------------------------------------
template <int K>
__device__ __forceinline__ void layer_to_lds(const float* __restrict__ in,
                                             float* __restrict__ Rrow,
                                             const float* __restrict__ W,
                                             const float* __restrict__ B) {
    #pragma unroll
    for (int o4 = 0; o4 < 16; ++o4) {
        const float4 bv = *(const float4*)&B[o4 * 4];
        float ax = bv.x, ay = bv.y, az = bv.z, aw = bv.w;
        #pragma unroll
        for (int i = 0; i < K; ++i) {
            const float4 wv = *(const float4*)&W[i * 64 + o4 * 4];
            const float fv = in[i];
            ax = fmaf(fv, wv.x, ax); ay = fmaf(fv, wv.y, ay);
            az = fmaf(fv, wv.z, az); aw = fmaf(fv, wv.w, aw);
        }
        Rrow[o4 * 4 + 0] = fmaxf(ax, 0.f);
        Rrow[o4 * 4 + 1] = fmaxf(ay, 0.f);
        Rrow[o4 * 4 + 2] = fmaxf(az, 0.f);
        Rrow[o4 * 4 + 3] = fmaxf(aw, 0.f);
    }
}

// ---------------------------------------------------------------------------
// Kernel B: one block per ray. 256 threads, thread t owns samples
// s = j*256 + t (wave = 64 consecutive samples -> coherent gathers).
// Hidden activations ping through a thread-private LDS row (stride 65 floats
// -> 2-way bank aliasing, free) so no per-thread array exceeds 64 floats.
// ---------------------------------------------------------------------------
#define RSTRIDE 65

__global__ __launch_bounds__(256)
void raymarch_kernel(const float* __restrict__ ro, const float* __restrict__ rd,
                     const float* __restrict__ vd, const float* __restrict__ grid,
                     const float* __restrict__ nrm,
                     const float* __restrict__ w0, const float* __restrict__ b0,
                     const float* __restrict__ w1, const float* __restrict__ b1,
                     const float* __restrict__ w2, const float* __restrict__ b2,
                     const float* __restrict__ w3, const float* __restrict__ b3,
                     float* __restrict__ out) {
    __shared__ __align__(16) float sw0[54 * 64];
    __shared__ __align__(16) float sw1[64 * 64];
    __shared__ __align__(16) float sw2[64 * 64];
    __shared__ __align__(16) float sw3[64 * 3];
    __shared__ __align__(16) float sb0[64], sb1[64], sb2[64];
    __shared__ float sb3[4];
    __shared__ float R[256 * RSTRIDE];   // per-thread hidden-activation row
    __shared__ float lgl[1024];
    __shared__ float aux[256];
    __shared__ float red[12];

    const int t = threadIdx.x;
    const int ray = blockIdx.x;
    float* const Rrow = R + t * RSTRIDE;

    for (int i = t; i < 54 * 64; i += 256) sw0[i] = w0[i];
    for (int i = t; i < 64 * 64; i += 256) sw1[i] = w1[i];
    for (int i = t; i < 64 * 64; i += 256) sw2[i] = w2[i];
    for (int i = t; i < 64 * 3;  i += 256) sw3[i] = w3[i];
    if (t < 64) { sb0[t] = b0[t]; sb1[t] = b1[t]; sb2[t] = b2[t]; }
    if (t < 3) sb3[t] = b3[t];
    if (t == 3) sb3[3] = 0.f;
    __syncthreads();

    const float ox = ro[ray * 3 + 0], oy = ro[ray * 3 + 1], oz = ro[ray * 3 + 2];
    const float dx = rd[ray * 3 + 0], dyv = rd[ray * 3 + 1], dzv = rd[ray * 3 + 2];
    const float vx = vd[ray * 3 + 0], vy = vd[ray * 3 + 1], vz = vd[ray * 3 + 2];

    // ray-box entry/exit (reference semantics)
    const float ex = (dx  == 0.f) ? 1e-6f : dx;
    const float ey = (dyv == 0.f) ? 1e-6f : dyv;
    const float ez = (dzv == 0.f) ? 1e-6f : dzv;
    const float rax = (1.f - ox) / ex, rbx = (-1.f - ox) / ex;
    const float ray_ = (1.f - oy) / ey, rby = (-1.f - oy) / ey;
    const float raz = (1.f - oz) / ez, rbz = (-1.f - oz) / ez;
    float tmin = fmaxf(fmaxf(fminf(rax, rbx), fminf(ray_, rby)), fminf(raz, rbz));
    float tmax = fminf(fminf(fmaxf(rax, rbx), fmaxf(ray_, rby)), fmaxf(raz, rbz));
    tmin = fminf(fmaxf(tmin, 0.2f), 3.0f);
    tmax = fminf(fmaxf(tmax, 0.2f), 3.0f);
    const bool mask_ray = (tmax <= tmin);
    const float invn = 1.0f / sqrtf(dx * dx + dyv * dyv + dzv * dzv);

    float alphas[4];
    float colr[4], colg[4], colb[4];

    for (int j = 0; j < 4; ++j) {
        alphas[j] = 0.f; colr[j] = 0.f; colg[j] = 0.f; colb[j] = 0.f;
        const int s = j * 256 + t;
        bool active = (s < N_SAMPLES) && !mask_ray;
        float px = 0.f, py = 0.f, pz = 0.f;
        if (active) {
            const float ti = tmin + STEP_T * (float)s * invn;
            px = fmaf(dx, ti, ox);
            py = fmaf(dyv, ti, oy);
            pz = fmaf(dzv, ti, oz);
            active = !(px < -1.f || px > 1.f || py < -1.f || py > 1.f ||
                       pz < -1.f || pz > 1.f);
        }
        if (active) {
            // trilinear setup; grid flat index = (ia*128 + ib)*128 + ic
            const float ga = (px + 1.f) * 63.5f;
            const float gb = (py + 1.f) * 63.5f;
            const float gc = (pz + 1.f) * 63.5f;
            const float fla = floorf(ga), flb = floorf(gb), flc = floorf(gc);
            const float fa = ga - fla, fb = gb - flb, fc = gc - flc;
            int ia0 = min(max((int)fla, 0), 127);
            int ib0 = min(max((int)flb, 0), 127);
            int ic0 = min(max((int)flc, 0), 127);
            int ia1 = min(ia0 + 1, 127);
            int ib1 = min(ib0 + 1, 127);
            int ic1 = min(ic0 + 1, 127);
            const int base00 = (ia0 * 128 + ib0) * 128;
            const int base01 = (ia0 * 128 + ib1) * 128;
            const int base10 = (ia1 * 128 + ib0) * 128;
            const int base11 = (ia1 * 128 + ib1) * 128;
            int idxs[8] = { base00 + ic0, base00 + ic1, base01 + ic0, base01 + ic1,
                            base10 + ic0, base10 + ic1, base11 + ic0, base11 + ic1 };
            const float wa0 = 1.f - fa, wb0 = 1.f - fb, wc0 = 1.f - fc;
            float w8[8] = { wa0 * wb0 * wc0, wa0 * wb0 * fc, wa0 * fb * wc0, wa0 * fb * fc,
                            fa  * wb0 * wc0, fa  * wb0 * fc, fa  * fb * wc0, fa  * fb * fc };

            float lat[16];
            #pragma unroll
            for (int c = 0; c < 16; ++c) {
                const float* gcp = grid + (size_t)c * V3;
                float acc = 0.f;
                #pragma unroll
                for (int k = 0; k < 8; ++k) acc = fmaf(w8[k], gcp[idxs[k]], acc);
                lat[c] = acc;
            }
            float n0 = 0.f, n1 = 0.f, n2 = 0.f;
            #pragma unroll
            for (int k = 0; k < 8; ++k) {
                const float* npk = nrm + (size_t)idxs[k] * 3;
                n0 = fmaf(w8[k], npk[0], n0);
                n1 = fmaf(w8[k], npk[1], n1);
                n2 = fmaf(w8[k], npk[2], n2);
            }
            const float nl = sqrtf(n0 * n0 + n1 * n1 + n2 * n2);
            const float ninv = -1.0f / fmaxf(nl, 1e-12f);
            n0 *= ninv; n1 *= ninv; n2 *= ninv;
            const float dotv = -(vx * n0 + vy * n1 + vz * n2);
            const float rx = fmaf(2.f * dotv, n0, vx);
            const float ry = fmaf(2.f * dotv, n1, vy);
            const float rz = fmaf(2.f * dotv, n2, vz);

            // alpha = 1 - exp(-softplus(lat0 + shift) * 0.5)
            const float d0 = lat[0] + ACT_SHIFT;
            const float sp = (d0 > 20.f) ? d0 : log1pf(expf(d0));
            alphas[j] = 1.f - expf(-sp * 0.5f);

            // feat = [rgb_lat(15), refdir(3), sin(18 freq-major), cos(18)]
            float feat[54];
            #pragma unroll
            for (int c = 0; c < 15; ++c) feat[c] = lat[c + 1];
            feat[15] = rx; feat[16] = ry; feat[17] = rz;
            float fr = 1.f;
            #pragma unroll
            for (int k = 0; k < 6; ++k) {
                feat[18 + k * 3 + 0] = sinf(rx * fr);
                feat[18 + k * 3 + 1] = sinf(ry * fr);
                feat[18 + k * 3 + 2] = sinf(rz * fr);
                feat[36 + k * 3 + 0] = cosf(rx * fr);
                feat[36 + k * 3 + 1] = cosf(ry * fr);
                feat[36 + k * 3 + 2] = cosf(rz * fr);
                fr *= 2.f;
            }

            // MLP: regs -> LDS row -> regs -> LDS row -> ... (peak ~85 VGPR)
            layer_to_lds<54>(feat, Rrow, sw0, sb0);
            {
                float h[64];
                #pragma unroll
                for (int k = 0; k < 64; ++k) h[k] = Rrow[k];
                layer_to_lds<64>(h, Rrow, sw1, sb1);
            }
            {
                float h[64];
                #pragma unroll
                for (int k = 0; k < 64; ++k) h[k] = Rrow[k];
                layer_to_lds<64>(h, Rrow, sw2, sb2);
            }
            {
                float h[64];
                #pragma unroll
                for (int k = 0; k < 64; ++k) h[k] = Rrow[k];
                float a0 = sb3[0], a1 = sb3[1], a2 = sb3[2];
                #pragma unroll
                for (int i = 0; i < 64; ++i) {
                    a0 = fmaf(h[i], sw3[i * 3 + 0], a0);
                    a1 = fmaf(h[i], sw3[i * 3 + 1], a1);
                    a2 = fmaf(h[i], sw3[i * 3 + 2], a2);
                }
                colr[j] = 1.f / (1.f + expf(-a0));
                colg[j] = 1.f / (1.f + expf(-a1));
                colb[j] = 1.f / (1.f + expf(-a2));
            }
        }
    }

    // log-space transmittance scan: lgl[s] = log(max(1-alpha,1e-10))
    #pragma unroll
    for (int j = 0; j < 4; ++j) {
        const int s = j * 256 + t;
        lgl[s] = logf(fmaxf(1.f - alphas[j], 1e-10f));
    }
    __syncthreads();
    // per-thread contiguous chunk inclusive scan
    float c0 = lgl[4 * t + 0];
    float c1 = c0 + lgl[4 * t + 1];
    float c2 = c1 + lgl[4 * t + 2];
    float c3 = c2 + lgl[4 * t + 3];
    lgl[4 * t + 0] = c0; lgl[4 * t + 1] = c1;
    lgl[4 * t + 2] = c2; lgl[4 * t + 3] = c3;
    aux[t] = c3;
    __syncthreads();
    // Hillis-Steele inclusive scan of chunk totals
    for (int off = 1; off < 256; off <<= 1) {
        const float v = (t >= off) ? aux[t - off] : 0.f;
        __syncthreads();
        aux[t] += v;
        __syncthreads();
    }
    const float total = aux[255];

    float r0 = 0.f, r1 = 0.f, r2 = 0.f;
    #pragma unroll
    for (int j = 0; j < 4; ++j) {
        const int s = j * 256 + t;
        if (s < N_SAMPLES && alphas[j] > 0.f) {
            float G;
            if (s == 0) G = 0.f;
            else {
                const int m = s - 1;
                G = lgl[m] + (((m >> 2) > 0) ? aux[(m >> 2) - 1] : 0.f);
            }
            const float T = expf(G);      // exclusive cumprod of (1-alpha)
            const float w = alphas[j] * T;
            r0 = fmaf(w, colr[j], r0);
            r1 = fmaf(w, colg[j], r1);
            r2 = fmaf(w, colb[j], r2);
        }
    }
    // block reduce (wave shuffle then LDS across 4 waves)
    #pragma unroll
    for (int off = 32; off > 0; off >>= 1) {
        r0 += __shfl_down(r0, off, 64);
        r1 += __shfl_down(r1, off, 64);
        r2 += __shfl_down(r2, off, 64);
    }
    if ((t & 63) == 0) {
        const int w = t >> 6;
        red[w * 3 + 0] = r0; red[w * 3 + 1] = r1; red[w * 3 + 2] = r2;
    }
    __syncthreads();
    if (t == 0) {
        const float Tf = expf(total);   // alphainv_cum[:, -1] * BG (BG=1)
        out[ray * 3 + 0] = red[0] + red[3] + red[6] + red[9]  + Tf;
        out[ray * 3 + 1] = red[1] + red[4] + red[7] + red[10] + Tf;
        out[ray * 3 + 2] = red[2] + red[5] + red[8] + red[11] + Tf;
    }
}

extern "C" void kernel_launch(void* const* d_in, const int* in_sizes, int n_in,
                              void* d_out, int out_size, void* d_ws, size_t ws_size,
                              hipStream_t stream) {
    (void)in_sizes; (void)n_in; (void)out_size; (void)ws_size;
    const float* ro    = (const float*)d_in[0];
    const float* rd    = (const float*)d_in[1];
    const float* vd    = (const float*)d_in[2];
    const float* grid  = (const float*)d_in[3];
    const float* sobel = (const float*)d_in[4];
    const float* w0 = (const float*)d_in[5];
    const float* b0 = (const float*)d_in[6];
    const float* w1 = (const float*)d_in[7];
    const float* b1 = (const float*)d_in[8];
    const float* w2 = (const float*)d_in[9];
    const float* b2 = (const float*)d_in[10];
    const float* w3 = (const float*)d_in[11];
    const float* b3 = (const float*)d_in[12];
    float* nrm = (float*)d_ws;                 // 3 * 128^3 floats = 25.2 MB

    normals_conv_kernel<<<V3 / 256, 256, 0, stream>>>(grid, sobel, nrm);
    raymarch_kernel<<<N_RAYS, 256, 0, stream>>>(ro, rd, vd, grid, nrm,
                                                w0, b0, w1, b1, w2, b2, w3, b3,
                                                (float*)d_out);
}